// Round 1
// baseline (207.791 us; speedup 1.0000x reference)
//
#include <hip/hip_runtime.h>

#define C_   256
#define H_   200
#define W_   200
#define PHB  7
#define PWB  7
#define SRS  2
#define GS   14          // PHB*SRS
#define NS   196         // GS*GS
#define BINS 49          // PHB*PWB
#define CHW  (H_*W_)     // 40000

__global__ __launch_bounds__(256) void roialign_fwd(
    const float* __restrict__ input,   // [4, 256, 200, 200]
    const float* __restrict__ rois,    // [K, 5]
    float* __restrict__ out,           // [K, 256, 7, 7]
    int K)
{
    __shared__ int   s_off[NS][4];
    __shared__ float s_wt [NS][4];

    const int k = blockIdx.x;
    if (k >= K) return;

    const float r0 = rois[k*5 + 0];
    const float rx1 = rois[k*5 + 1];
    const float ry1 = rois[k*5 + 2];
    const float rx2 = rois[k*5 + 3];
    const float ry2 = rois[k*5 + 4];
    const int bidx = (int)r0;

    // ALIGNED=True: start = coord*SCALE - 0.5 ; bin size = (span*SCALE)/7
    // match numpy op order exactly (no fma contraction) for boundary safety
    const float sx = __fsub_rn(__fmul_rn(rx1, 0.25f), 0.5f);
    const float sy = __fsub_rn(__fmul_rn(ry1, 0.25f), 0.5f);
    const float rw = __fmul_rn(__fsub_rn(rx2, rx1), 0.25f);
    const float rh = __fmul_rn(__fsub_rn(ry2, ry1), 0.25f);
    const float bw = __fdiv_rn(rw, 7.0f);
    const float bh = __fdiv_rn(rh, 7.0f);

    const int tid = threadIdx.x;

    // ---- phase 1: 196 sample points -> offsets + weights in LDS ----
    if (tid < NS) {
        const int gy = tid / GS;
        const int gx = tid - gy * GS;
        // grid coord = bin_index + (sub+0.5)/SR  with sub in {0,1} -> 0.25/0.75
        const float cy = (float)(gy >> 1) + ((float)(gy & 1) + 0.5f) * 0.5f;
        const float cx = (float)(gx >> 1) + ((float)(gx & 1) + 0.5f) * 0.5f;
        const float fy = __fadd_rn(sy, __fmul_rn(cy, bh));
        const float fx = __fadd_rn(sx, __fmul_rn(cx, bw));

        const bool valid = (fy >= -1.0f) && (fy <= (float)H_) &&
                           (fx >= -1.0f) && (fx <= (float)W_);

        float y = fminf(fmaxf(fy, 0.0f), (float)(H_ - 1));
        float x = fminf(fmaxf(fx, 0.0f), (float)(W_ - 1));
        int y0 = (int)floorf(y);
        int x0 = (int)floorf(x);
        int y1 = min(y0 + 1, H_ - 1);
        int x1 = min(x0 + 1, W_ - 1);
        float ly = y - (float)y0;
        float lx = x - (float)x0;
        float hy = 1.0f - ly, hx = 1.0f - lx;

        float w00 = hy * hx, w01 = hy * lx, w10 = ly * hx, w11 = ly * lx;
        if (!valid) { w00 = w01 = w10 = w11 = 0.0f; }

        s_off[tid][0] = y0 * W_ + x0;
        s_off[tid][1] = y0 * W_ + x1;
        s_off[tid][2] = y1 * W_ + x0;
        s_off[tid][3] = y1 * W_ + x1;
        s_wt [tid][0] = w00;
        s_wt [tid][1] = w01;
        s_wt [tid][2] = w10;
        s_wt [tid][3] = w11;
    }
    __syncthreads();

    // ---- phase 2: 256*49 outputs, output-layout order (coalesced stores) ----
    const float* __restrict__ img  = input + (size_t)bidx * C_ * CHW;
    float* __restrict__       outk = out   + (size_t)k * C_ * BINS;

    #pragma unroll 1
    for (int e = tid; e < C_ * BINS; e += 256) {
        const int c   = e / BINS;
        const int bin = e - c * BINS;
        const int ph  = bin / PWB;
        const int pw  = bin - ph * PWB;
        const float* __restrict__ ch = img + c * CHW;

        const int s0 = (2 * ph) * GS + 2 * pw;   // top-left sample of 2x2 group
        float acc = 0.0f;
        #pragma unroll
        for (int q = 0; q < 4; ++q) {
            const int s = s0 + (q >> 1) * GS + (q & 1);
            acc += s_wt[s][0] * ch[s_off[s][0]]
                 + s_wt[s][1] * ch[s_off[s][1]]
                 + s_wt[s][2] * ch[s_off[s][2]]
                 + s_wt[s][3] * ch[s_off[s][3]];
        }
        outk[e] = acc * 0.25f;
    }
}

extern "C" void kernel_launch(void* const* d_in, const int* in_sizes, int n_in,
                              void* d_out, int out_size, void* d_ws, size_t ws_size,
                              hipStream_t stream) {
    const float* input = (const float*)d_in[0];
    const float* rois  = (const float*)d_in[1];
    float* out = (float*)d_out;
    const int K = in_sizes[1] / 5;

    roialign_fwd<<<K, 256, 0, stream>>>(input, rois, out, K);
}

// Round 3
// 173.288 us; speedup vs baseline: 1.1991x; 1.1991x over previous
//
#include <hip/hip_runtime.h>

#define C_     256
#define H_     200
#define W_     200
#define PWB    7
#define BINS   49            // 7*7
#define CHW    (H_*W_)       // 40000
#define CSPLIT 4
#define CB     (C_/CSPLIT)   // 64 channels per block
#define NCG    5             // channel groups: ceil(256/49) active = 5

__global__ __launch_bounds__(256) void roialign_fwd(
    const float* __restrict__ input,   // [4, 256, 200, 200]
    const float* __restrict__ rois,    // [K, 5]
    float* __restrict__ out,           // [K, 256, 7, 7]
    int K)
{
    const int k  = blockIdx.x / CSPLIT;
    const int cs = blockIdx.x - k * CSPLIT;
    if (k >= K) return;

    const int tid = threadIdx.x;
    const int bin = tid % BINS;       // 0..48
    const int cg  = tid / BINS;       // 0..5
    if (cg >= NCG) return;            // 11 idle threads, no barrier anywhere

    // ---- roi params (block-uniform -> scalar regs) ----
    const float rx1 = rois[k*5 + 1];
    const float ry1 = rois[k*5 + 2];
    const float rx2 = rois[k*5 + 3];
    const float ry2 = rois[k*5 + 4];
    const int  bidx = (int)rois[k*5 + 0];

    // ALIGNED=True: start = coord*0.25 - 0.5 ; bin size = (span*0.25)/7
    // op order matches the numpy reference exactly
    const float sx = __fsub_rn(__fmul_rn(rx1, 0.25f), 0.5f);
    const float sy = __fsub_rn(__fmul_rn(ry1, 0.25f), 0.5f);
    const float rw = __fmul_rn(__fsub_rn(rx2, rx1), 0.25f);
    const float rh = __fmul_rn(__fsub_rn(ry2, ry1), 0.25f);
    const float bw = __fdiv_rn(rw, 7.0f);
    const float bh = __fdiv_rn(rh, 7.0f);

    const int ph = bin / PWB;
    const int pw = bin - ph * PWB;

    // ---- this thread's 4 sample points (2x2 subsamples of its bin) ----
    // fully unrolled -> everything stays in registers (static indexing)
    int   off[4][4];
    float wt [4][4];
    #pragma unroll
    for (int q = 0; q < 4; ++q) {
        // grid coord = bin_index + (sub+0.5)/SR, sub in {0,1} -> +0.25 / +0.75
        const float cy = (float)ph + ((q >> 1) ? 0.75f : 0.25f);
        const float cx = (float)pw + ((q & 1)  ? 0.75f : 0.25f);
        const float fy = __fadd_rn(sy, __fmul_rn(cy, bh));
        const float fx = __fadd_rn(sx, __fmul_rn(cx, bw));

        const bool valid = (fy >= -1.0f) && (fy <= (float)H_) &&
                           (fx >= -1.0f) && (fx <= (float)W_);

        const float y = fminf(fmaxf(fy, 0.0f), (float)(H_ - 1));
        const float x = fminf(fmaxf(fx, 0.0f), (float)(W_ - 1));
        const int y0 = (int)floorf(y);
        const int x0 = (int)floorf(x);
        const int y1 = min(y0 + 1, H_ - 1);
        const int x1 = min(x0 + 1, W_ - 1);
        const float ly = y - (float)y0;
        const float lx = x - (float)x0;
        const float hy = 1.0f - ly, hx = 1.0f - lx;

        float w00 = hy * hx, w01 = hy * lx, w10 = ly * hx, w11 = ly * lx;
        if (!valid) { w00 = w01 = w10 = w11 = 0.0f; }

        off[q][0] = y0 * W_ + x0;
        off[q][1] = y0 * W_ + x1;
        off[q][2] = y1 * W_ + x0;
        off[q][3] = y1 * W_ + x1;
        wt [q][0] = w00;
        wt [q][1] = w01;
        wt [q][2] = w10;
        wt [q][3] = w11;
    }

    // ---- gather loop over this block's 64 channels ----
    const float* __restrict__ img  = input + ((size_t)bidx * C_ + cs * CB) * CHW;
    float* __restrict__       outk = out   + ((size_t)k    * C_ + cs * CB) * BINS;

    #pragma unroll 2
    for (int c = cg; c < CB; c += NCG) {
        const float* __restrict__ ch = img + c * CHW;
        float acc = 0.0f;
        #pragma unroll
        for (int q = 0; q < 4; ++q) {
            acc += wt[q][0] * ch[off[q][0]]
                 + wt[q][1] * ch[off[q][1]]
                 + wt[q][2] * ch[off[q][2]]
                 + wt[q][3] * ch[off[q][3]];
        }
        outk[c * BINS + bin] = acc * 0.25f;
    }
}

extern "C" void kernel_launch(void* const* d_in, const int* in_sizes, int n_in,
                              void* d_out, int out_size, void* d_ws, size_t ws_size,
                              hipStream_t stream) {
    const float* input = (const float*)d_in[0];
    const float* rois  = (const float*)d_in[1];
    float* out = (float*)d_out;
    const int K = in_sizes[1] / 5;

    roialign_fwd<<<K * CSPLIT, 256, 0, stream>>>(input, rois, out, K);
}

// Round 4
// 160.590 us; speedup vs baseline: 1.2939x; 1.0791x over previous
//
#include <hip/hip_runtime.h>

#define C_     256
#define H_     200
#define W_     200
#define PWB    7
#define BINS   49            // 7*7
#define CHW    (H_*W_)       // 40000
#define CSPLIT 4
#define CB     (C_/CSPLIT)   // 64 channels per block
#define NCG    5             // ceil(256/49) active channel-groups

// 8-byte pair with 4-byte alignment: lets hipcc emit global_load_dwordx2
// at dword (not 8B) alignment.
typedef struct __attribute__((aligned(4))) { float x, y; } f2u;

__global__ __launch_bounds__(256) void roialign_fwd(
    const float* __restrict__ input,   // [4, 256, 200, 200]
    const float* __restrict__ rois,    // [K, 5]
    float* __restrict__ out,           // [K, 256, 7, 7]
    int K)
{
    const int k  = blockIdx.x / CSPLIT;
    const int cs = blockIdx.x - k * CSPLIT;
    if (k >= K) return;

    const int tid = threadIdx.x;
    const int bin = tid % BINS;       // 0..48
    const int cg  = tid / BINS;       // 0..5
    if (cg >= NCG) return;            // 11 idle threads; no barriers anywhere

    // ---- roi params ----
    const float rx1 = rois[k*5 + 1];
    const float ry1 = rois[k*5 + 2];
    const float rx2 = rois[k*5 + 3];
    const float ry2 = rois[k*5 + 4];
    const int  bidx = (int)rois[k*5 + 0];

    // ALIGNED=True: start = coord*0.25 - 0.5 ; bin size = (span*0.25)/7
    const float sx = __fsub_rn(__fmul_rn(rx1, 0.25f), 0.5f);
    const float sy = __fsub_rn(__fmul_rn(ry1, 0.25f), 0.5f);
    const float rw = __fmul_rn(__fsub_rn(rx2, rx1), 0.25f);
    const float rh = __fmul_rn(__fsub_rn(ry2, ry1), 0.25f);
    const float bw = __fdiv_rn(rw, 7.0f);
    const float bh = __fdiv_rn(rh, 7.0f);

    const int ph = bin / PWB;
    const int pw = bin - ph * PWB;

    // ---- per-sample precompute: 2 row offsets + 4 pair-weights each ----
    // corner pair (v00,v01) merges into one float2 at row y0, (v10,v11) at y1.
    // right-edge clamp (x0==W-1): load at W-2, shift weight onto .y lane.
    int   off0[4], off1[4];
    float wA0[4], wB0[4], wA1[4], wB1[4];
    #pragma unroll
    for (int q = 0; q < 4; ++q) {
        const float cy = (float)ph + ((q >> 1) ? 0.75f : 0.25f);
        const float cx = (float)pw + ((q & 1)  ? 0.75f : 0.25f);
        const float fy = __fadd_rn(sy, __fmul_rn(cy, bh));
        const float fx = __fadd_rn(sx, __fmul_rn(cx, bw));

        const bool valid = (fy >= -1.0f) && (fy <= (float)H_) &&
                           (fx >= -1.0f) && (fx <= (float)W_);

        const float y = fminf(fmaxf(fy, 0.0f), (float)(H_ - 1));
        const float x = fminf(fmaxf(fx, 0.0f), (float)(W_ - 1));
        const int y0 = (int)floorf(y);
        const int x0 = (int)floorf(x);
        const int y1 = min(y0 + 1, H_ - 1);
        const float ly = y - (float)y0;
        const float lx = x - (float)x0;
        const float hy = 1.0f - ly, hx = 1.0f - lx;

        float w00 = hy * hx, w01 = hy * lx, w10 = ly * hx, w11 = ly * lx;
        if (!valid) { w00 = w01 = w10 = w11 = 0.0f; }

        const int xb = min(x0, W_ - 2);
        const bool xcl = (x0 != xb);          // x0 == W-1 -> w01,w11 already 0
        wA0[q] = xcl ? 0.0f : w00;
        wB0[q] = xcl ? w00  : w01;
        wA1[q] = xcl ? 0.0f : w10;
        wB1[q] = xcl ? w10  : w11;
        off0[q] = y0 * W_ + xb;
        off1[q] = y1 * W_ + xb;
    }

    // ---- gather loop over this block's 64 channels ----
    const float* __restrict__ img  = input + ((size_t)bidx * C_ + cs * CB) * CHW;
    float* __restrict__       outk = out   + ((size_t)k    * C_ + cs * CB) * BINS;

    #pragma unroll 2
    for (int c = cg; c < CB; c += NCG) {
        const float* __restrict__ ch = img + c * CHW;
        float acc = 0.0f;
        #pragma unroll
        for (int q = 0; q < 4; ++q) {
            const f2u p0 = *(const f2u*)(ch + off0[q]);
            const f2u p1 = *(const f2u*)(ch + off1[q]);
            acc += wA0[q] * p0.x + wB0[q] * p0.y
                 + wA1[q] * p1.x + wB1[q] * p1.y;
        }
        outk[c * BINS + bin] = acc * 0.25f;
    }
}

extern "C" void kernel_launch(void* const* d_in, const int* in_sizes, int n_in,
                              void* d_out, int out_size, void* d_ws, size_t ws_size,
                              hipStream_t stream) {
    const float* input = (const float*)d_in[0];
    const float* rois  = (const float*)d_in[1];
    float* out = (float*)d_out;
    const int K = in_sizes[1] / 5;

    roialign_fwd<<<K * CSPLIT, 256, 0, stream>>>(input, rois, out, K);
}